// Round 1
// baseline (2105.215 us; speedup 1.0000x reference)
//
#include <hip/hip_runtime.h>
#include <math.h>

// ---------------------------------------------------------------------------
// DETR deformable-transformer encoder layer, MI355X.
// Constants: D=512, H=8, DFF=2048, K=4, S=4, DH=64, B=4
// Shapes: (56,56),(28,28),(14,14),(7,7) -> tokens/scale (incl. batch):
//   12544, 3136, 784, 196 ; total T = 16660 ; per-batch Lq = 4165
// Input order (setup_inputs dict order, interleaved!):
//   0 src0, 1 ref0, 2 src1, 3 ref1, 4 src2, 5 ref2, 6 src3, 7 ref3,
//   8 Wv, 9 bv, 10 Woff, 11 boff, 12 Wattn, 13 battn, 14 Wo, 15 bo,
//   16 W1, 17 b1, 18 W2, 19 b2, 20 g1, 21 be1, 22 g2, 23 be2
// ---------------------------------------------------------------------------

#define TTOT 16660
#define LQTOT 4165

// token t -> row in d_out ([B, 4165, 512], scales concatenated per batch)
__device__ __forceinline__ int permute_row(int t) {
    int off, area, qoff;
    if (t < 12544)      { off = 0;     area = 3136; qoff = 0;    }
    else if (t < 15680) { off = 12544; area = 784;  qoff = 3136; }
    else if (t < 16464) { off = 15680; area = 196;  qoff = 3920; }
    else                { off = 16464; area = 49;   qoff = 4116; }
    int rel = t - off;
    int b = rel / area;
    int pos = rel - b * area;
    return b * LQTOT + qoff + pos;
}

enum { EPI_BIAS = 0, EPI_RELU = 1, EPI_RESID = 2, EPI_RESID_SCATTER = 3 };

// C = A[M,Kd] @ Wm[Kd,N] + bias (+ residual) (+ relu) (+ scatter rows)
// 64x64 tile, BK=16, 256 threads, 4x4 microtile per thread.
template <int EPI>
__global__ __launch_bounds__(256) void gemm_f32(
    const float* __restrict__ A, const float* __restrict__ Wm,
    const float* __restrict__ bias, const float* __restrict__ Rres,
    float* __restrict__ Cout, int M, int N, int Kd)
{
    __shared__ float As[16][68];   // [k][m], padded to keep 16B alignment off
    __shared__ float Ws[16][64];   // [k][n]
    const int tid = threadIdx.x;
    const int m0 = blockIdx.y * 64;
    const int n0 = blockIdx.x * 64;
    const int ty = tid >> 4, tx = tid & 15;
    const int am = tid >> 2;            // 0..63 row within A tile
    const int ak = (tid & 3) << 2;      // 0,4,8,12
    const int wk = tid >> 4;            // 0..15 row within W tile
    const int wn = (tid & 15) << 2;     // 0..60
    float acc[4][4] = {};
    const bool aok = (m0 + am) < M;
    const float* Ap = A + (size_t)(m0 + am) * Kd + ak;
    const float* Wp = Wm + (size_t)wk * N + n0 + wn;

    for (int k0 = 0; k0 < Kd; k0 += 16) {
        float4 av = aok ? *(const float4*)Ap : make_float4(0.f, 0.f, 0.f, 0.f);
        float4 wv = *(const float4*)Wp;
        Ap += 16; Wp += (size_t)16 * N;
        __syncthreads();
        As[ak + 0][am] = av.x; As[ak + 1][am] = av.y;
        As[ak + 2][am] = av.z; As[ak + 3][am] = av.w;
        *(float4*)&Ws[wk][wn] = wv;
        __syncthreads();
        #pragma unroll
        for (int kk = 0; kk < 16; ++kk) {
            float a0 = As[kk][ty * 4 + 0];
            float a1 = As[kk][ty * 4 + 1];
            float a2 = As[kk][ty * 4 + 2];
            float a3 = As[kk][ty * 4 + 3];
            float b0 = Ws[kk][tx * 4 + 0];
            float b1 = Ws[kk][tx * 4 + 1];
            float b2 = Ws[kk][tx * 4 + 2];
            float b3 = Ws[kk][tx * 4 + 3];
            acc[0][0] += a0 * b0; acc[0][1] += a0 * b1; acc[0][2] += a0 * b2; acc[0][3] += a0 * b3;
            acc[1][0] += a1 * b0; acc[1][1] += a1 * b1; acc[1][2] += a1 * b2; acc[1][3] += a1 * b3;
            acc[2][0] += a2 * b0; acc[2][1] += a2 * b1; acc[2][2] += a2 * b2; acc[2][3] += a2 * b3;
            acc[3][0] += a3 * b0; acc[3][1] += a3 * b1; acc[3][2] += a3 * b2; acc[3][3] += a3 * b3;
        }
    }

    #pragma unroll
    for (int i = 0; i < 4; ++i) {
        int row = m0 + ty * 4 + i;
        if (row >= M) continue;
        int col = n0 + tx * 4;
        float4 r = make_float4(acc[i][0] + bias[col + 0],
                               acc[i][1] + bias[col + 1],
                               acc[i][2] + bias[col + 2],
                               acc[i][3] + bias[col + 3]);
        if (EPI == EPI_RELU) {
            r.x = fmaxf(r.x, 0.f); r.y = fmaxf(r.y, 0.f);
            r.z = fmaxf(r.z, 0.f); r.w = fmaxf(r.w, 0.f);
        }
        size_t orow = (size_t)row;
        if (EPI == EPI_RESID || EPI == EPI_RESID_SCATTER) {
            float4 rv = *(const float4*)&Rres[(size_t)row * N + col];
            r.x += rv.x; r.y += rv.y; r.z += rv.z; r.w += rv.w;
            if (EPI == EPI_RESID_SCATTER) orow = (size_t)permute_row(row);
        }
        *(float4*)&Cout[orow * (size_t)N + col] = r;
    }
}

// One wave per (token, head): softmax over S*K=16 logits, bilinear-sample the
// 4 value pyramids, weighted-accumulate 64 channels (one per lane).
__global__ __launch_bounds__(256) void sample_attn(
    const float* __restrict__ Vp, const float* __restrict__ OFFB,
    const float* __restrict__ ATT, const float* __restrict__ RF,
    float* __restrict__ ACC)
{
    int wid = (blockIdx.x << 2) + (threadIdx.x >> 6);
    if (wid >= TTOT * 8) return;
    const int lane = threadIdx.x & 63;
    const int t = wid >> 3;
    const int h = wid & 7;

    int soff, area;
    if (t < 12544)      { soff = 0;     area = 3136; }
    else if (t < 15680) { soff = 12544; area = 784;  }
    else if (t < 16464) { soff = 15680; area = 196;  }
    else                { soff = 16464; area = 49;   }
    const int b = (t - soff) / area;

    // softmax over the 16 (level,k) logits of this head
    const float* at = ATT + (size_t)t * 128 + h * 16;
    float wv[16];
    float mx = -1e30f;
    #pragma unroll
    for (int j = 0; j < 16; ++j) { wv[j] = at[j]; mx = fmaxf(mx, wv[j]); }
    float sum = 0.f;
    #pragma unroll
    for (int j = 0; j < 16; ++j) { wv[j] = __expf(wv[j] - mx); sum += wv[j]; }
    const float inv = 1.f / sum;

    const float rx = RF[t * 2 + 0];
    const float ry = RF[t * 2 + 1];
    const float* ob = OFFB + (size_t)t * 256 + h * 32;

    float acc = 0.f;
    #pragma unroll
    for (int li = 0; li < 4; ++li) {
        const int wl = (li == 0) ? 56 : (li == 1) ? 28 : (li == 2) ? 14 : 7;
        const int hl = wl;
        const int vtok0 = ((li == 0) ? 0 : (li == 1) ? 12544 : (li == 2) ? 15680 : 16464)
                          + b * wl * hl;
        const float* vb = Vp + (size_t)vtok0 * 512 + h * 64 + lane;
        #pragma unroll
        for (int k = 0; k < 4; ++k) {
            const float ox = ob[(li * 4 + k) * 2 + 0];
            const float oy = ob[(li * 4 + k) * 2 + 1];
            // faithful to ref: loc = ref + off/scale ; x = loc*wl - 0.5
            const float x = (rx + ox / (float)wl) * (float)wl - 0.5f;
            const float y = (ry + oy / (float)hl) * (float)hl - 0.5f;
            const float x0f = floorf(x), y0f = floorf(y);
            const float wx1 = x - x0f, wx0 = 1.f - wx1;
            const float wy1 = y - y0f, wy0 = 1.f - wy1;
            const int x0 = (int)x0f, y0 = (int)y0f;
            const int x1 = x0 + 1, y1 = y0 + 1;
            const bool vx0 = (x0 >= 0) & (x0 < wl);
            const bool vx1 = (x1 >= 0) & (x1 < wl);
            const bool vy0 = (y0 >= 0) & (y0 < hl);
            const bool vy1 = (y1 >= 0) & (y1 < hl);
            float sv = 0.f;
            if (vx0 & vy0) sv += wx0 * wy0 * vb[(size_t)(y0 * wl + x0) * 512];
            if (vx1 & vy0) sv += wx1 * wy0 * vb[(size_t)(y0 * wl + x1) * 512];
            if (vx0 & vy1) sv += wx0 * wy1 * vb[(size_t)(y1 * wl + x0) * 512];
            if (vx1 & vy1) sv += wx1 * wy1 * vb[(size_t)(y1 * wl + x1) * 512];
            acc += (wv[li * 4 + k] * inv) * sv;
        }
    }
    ACC[(size_t)t * 512 + h * 64 + lane] = acc;
}

// In-place layernorm over rows of 512, one 256-thread block per row.
__global__ __launch_bounds__(256) void ln_inplace(
    float* __restrict__ X, const float* __restrict__ g, const float* __restrict__ be)
{
    const int row = blockIdx.x;
    float* xr = X + (size_t)row * 512;
    const int tid = threadIdx.x;
    float v0 = xr[tid];
    float v1 = xr[tid + 256];
    float s = v0 + v1;
    float ss = v0 * v0 + v1 * v1;
    #pragma unroll
    for (int o = 32; o > 0; o >>= 1) {
        s += __shfl_down(s, o, 64);
        ss += __shfl_down(ss, o, 64);
    }
    __shared__ float sm[4], sm2[4];
    const int w = tid >> 6;
    if ((tid & 63) == 0) { sm[w] = s; sm2[w] = ss; }
    __syncthreads();
    if (tid == 0) {
        sm[0] = sm[0] + sm[1] + sm[2] + sm[3];
        sm2[0] = sm2[0] + sm2[1] + sm2[2] + sm2[3];
    }
    __syncthreads();
    const float mu = sm[0] * (1.f / 512.f);
    const float var = sm2[0] * (1.f / 512.f) - mu * mu;
    const float rs = rsqrtf(var + 1e-5f);
    xr[tid]       = (v0 - mu) * rs * g[tid]       + be[tid];
    xr[tid + 256] = (v1 - mu) * rs * g[tid + 256] + be[tid + 256];
}

extern "C" void kernel_launch(void* const* d_in, const int* in_sizes, int n_in,
                              void* d_out, int out_size, void* d_ws, size_t ws_size,
                              hipStream_t stream)
{
    const float* src[4] = { (const float*)d_in[0], (const float*)d_in[2],
                            (const float*)d_in[4], (const float*)d_in[6] };
    const float* ref[4] = { (const float*)d_in[1], (const float*)d_in[3],
                            (const float*)d_in[5], (const float*)d_in[7] };
    const float* Wv    = (const float*)d_in[8];
    const float* bv    = (const float*)d_in[9];
    const float* Woff  = (const float*)d_in[10];
    const float* boff  = (const float*)d_in[11];
    const float* Wattn = (const float*)d_in[12];
    const float* battn = (const float*)d_in[13];
    const float* Wo    = (const float*)d_in[14];
    const float* bo    = (const float*)d_in[15];
    const float* W1    = (const float*)d_in[16];
    const float* b1    = (const float*)d_in[17];
    const float* W2    = (const float*)d_in[18];
    const float* b2    = (const float*)d_in[19];
    const float* g1    = (const float*)d_in[20];
    const float* be1   = (const float*)d_in[21];
    const float* g2    = (const float*)d_in[22];
    const float* be2   = (const float*)d_in[23];

    // workspace layout (floats). F aliases [Q..RF] (dead by the time F is written).
    constexpr size_t NT512 = (size_t)TTOT * 512;   //  8,529,920
    constexpr size_t NT256 = (size_t)TTOT * 256;
    constexpr size_t NT128 = (size_t)TTOT * 128;
    float* ws   = (float*)d_ws;
    float* Q    = ws;                       // [T,512]
    float* Vp   = ws + NT512;               // [T,512]
    float* ACC  = ws + 2 * NT512;           // [T,512]
    float* OFFB = ws + 3 * NT512;           // [T,256]
    float* ATT  = OFFB + NT256;             // [T,128]
    float* RF   = ATT + NT128;              // [T,2]
    float* F    = ws;                       // [T,2048] aliases Q..RF
    float* X1   = ws + (size_t)TTOT * 2048; // [T,512]
    float* out  = (float*)d_out;

    // concat srcs/refs into contiguous token-major buffers (layouts match)
    const int tokoff[4] = { 0, 12544, 15680, 16464 };
    const int ntok[4]   = { 12544, 3136, 784, 196 };
    for (int l = 0; l < 4; ++l) {
        hipMemcpyAsync(Q + (size_t)tokoff[l] * 512, src[l],
                       (size_t)ntok[l] * 512 * sizeof(float),
                       hipMemcpyDeviceToDevice, stream);
        hipMemcpyAsync(RF + (size_t)tokoff[l] * 2, ref[l],
                       (size_t)ntok[l] * 2 * sizeof(float),
                       hipMemcpyDeviceToDevice, stream);
    }

    const dim3 blk(256);
    const int mt = (TTOT + 63) / 64;  // 261

    // value / offset / attention projections
    gemm_f32<EPI_BIAS><<<dim3(8,  mt), blk, 0, stream>>>(Q, Wv,    bv,    nullptr, Vp,   TTOT, 512,  512);
    gemm_f32<EPI_BIAS><<<dim3(4,  mt), blk, 0, stream>>>(Q, Woff,  boff,  nullptr, OFFB, TTOT, 256,  512);
    gemm_f32<EPI_BIAS><<<dim3(2,  mt), blk, 0, stream>>>(Q, Wattn, battn, nullptr, ATT,  TTOT, 128,  512);

    // deformable sampling + attention-weighted accumulate
    sample_attn<<<dim3((TTOT * 8 + 3) / 4), blk, 0, stream>>>(Vp, OFFB, ATT, RF, ACC);

    // output projection + residual, layernorm 1
    gemm_f32<EPI_RESID><<<dim3(8, mt), blk, 0, stream>>>(ACC, Wo, bo, Q, X1, TTOT, 512, 512);
    ln_inplace<<<dim3(TTOT), blk, 0, stream>>>(X1, g1, be1);

    // FFN
    gemm_f32<EPI_RELU><<<dim3(32, mt), blk, 0, stream>>>(X1, W1, b1, nullptr, F, TTOT, 2048, 512);
    gemm_f32<EPI_RESID_SCATTER><<<dim3(8, mt), blk, 0, stream>>>(F, W2, b2, X1, out, TTOT, 512, 2048);
    ln_inplace<<<dim3(TTOT), blk, 0, stream>>>(out, g2, be2);
}

// Round 2
// 710.656 us; speedup vs baseline: 2.9624x; 2.9624x over previous
//
#include <hip/hip_runtime.h>
#include <math.h>

// ---------------------------------------------------------------------------
// DETR deformable-transformer encoder layer, MI355X — bf16 MFMA version.
// D=512, H=8, DFF=2048, K=4, S=4, DH=64, B=4
// token counts per scale (incl. batch): 12544, 3136, 784, 196 ; T=16660
// ---------------------------------------------------------------------------

#define TTOT 16660
#define TPAD 16768   // 131 * 128
#define LQTOT 4165

typedef __attribute__((ext_vector_type(8))) short bf16x8;
typedef __attribute__((ext_vector_type(4))) float f32x4;

typedef __attribute__((address_space(1))) const unsigned int g_u32;
typedef __attribute__((address_space(3))) unsigned int l_u32;

__device__ __forceinline__ unsigned short f2bf(float f) {
    unsigned u = __builtin_bit_cast(unsigned, f);
    u += 0x7fffu + ((u >> 16) & 1u);
    return (unsigned short)(u >> 16);
}
__device__ __forceinline__ float bf2f(unsigned short s) {
    unsigned u = ((unsigned)s) << 16;
    return __builtin_bit_cast(float, u);
}

// token row -> row in d_out ([B, 4165, 512], scales concatenated per batch)
__device__ __forceinline__ int permute_row(int t) {
    int off, area, qoff;
    if (t < 12544)      { off = 0;     area = 3136; qoff = 0;    }
    else if (t < 15680) { off = 12544; area = 784;  qoff = 3136; }
    else if (t < 16464) { off = 15680; area = 196;  qoff = 3920; }
    else                { off = 16464; area = 49;   qoff = 4116; }
    int rel = t - off;
    int b = rel / area;
    int pos = rel - b * area;
    return b * LQTOT + qoff + pos;
}

// token row -> fp32 row pointer inside the 4 concatenated src arrays
__device__ __forceinline__ const float* src_row(int row, const float* s0, const float* s1,
                                                const float* s2, const float* s3) {
    if (row < 12544) return s0 + (size_t)row * 512;
    if (row < 15680) return s1 + (size_t)(row - 12544) * 512;
    if (row < 16464) return s2 + (size_t)(row - 15680) * 512;
    return s3 + (size_t)(row - 16464) * 512;
}

__device__ __forceinline__ void async_copy16(const unsigned short* g, unsigned short* lds_wave_uniform) {
    __builtin_amdgcn_global_load_lds((g_u32*)g, (l_u32*)lds_wave_uniform, 16, 0, 0);
}

// ---------------------------------------------------------------------------
// bf16 MFMA GEMM: C = A[M,Kd] @ (Bt[N,Kd])^T (+bias)(+epilogue)
// 128x128 tile, BK=32, 256 threads = 4 waves (2x2 of 64x64), 16x16x32 MFMA.
// LDS k-chunk XOR swizzle -> max 2-way bank aliasing on ds_read_b128 (free).
// ---------------------------------------------------------------------------
enum { EPI_SPLIT = 0, EPI_RESID_SRC = 1, EPI_RELU = 2, EPI_RESID_SCATTER = 3 };

struct GemmArgs {
    const unsigned short* A;    // [Mpad, Kd] bf16
    const unsigned short* Bt;   // [N, Kd]   bf16 (W^T)
    const float* bias0; const float* bias1; const float* bias2;
    const unsigned short* residb;   // bf16 residual (scatter epi)
    const float* s0; const float* s1; const float* s2; const float* s3; // fp32 resid gather
    void* out0; unsigned short* out1; unsigned short* out2;
    int M, N, Kd;
};

template <int EPI>
__global__ __launch_bounds__(256) void gemm_mfma(GemmArgs a)
{
    __shared__ unsigned short As[128 * 32];
    __shared__ unsigned short Bs[128 * 32];
    const int tid  = threadIdx.x;
    const int wave = tid >> 6;
    const int lane = tid & 63;
    const int m0 = blockIdx.y * 128;
    const int n0 = blockIdx.x * 128;

    // staging: thread -> (row = tid>>2 [+64 for 2nd instr], lds slot = tid&3)
    // LDS slot s of row r holds global k-chunk s ^ ((r>>1)&3)
    const int srow = tid >> 2;
    const int kg   = (tid & 3) ^ ((tid >> 3) & 3);
    const unsigned short* Ag = a.A  + (size_t)(m0 + srow) * a.Kd + kg * 8;
    const unsigned short* Bg = a.Bt + (size_t)(n0 + srow) * a.Kd + kg * 8;
    const size_t rstep = (size_t)64 * a.Kd;
    unsigned short* ldsA0 = As + wave * 512;
    unsigned short* ldsA1 = As + 2048 + wave * 512;
    unsigned short* ldsB0 = Bs + wave * 512;
    unsigned short* ldsB1 = Bs + 2048 + wave * 512;

    const int wm = (wave >> 1) << 6;
    const int wn = (wave & 1) << 6;
    const int fm = lane & 15;
    const int fq = lane >> 4;
    const int slot = (fq ^ ((fm >> 1) & 3)) << 3;   // ushort offset of this lane's k-chunk

    const f32x4 fzero = {0.f, 0.f, 0.f, 0.f};
    f32x4 acc[4][4];
#pragma unroll
    for (int i = 0; i < 4; ++i)
#pragma unroll
        for (int j = 0; j < 4; ++j) acc[i][j] = fzero;

    for (int k0 = 0; k0 < a.Kd; k0 += 32) {
        __syncthreads();                    // all waves done reading LDS
        async_copy16(Ag + k0,         ldsA0);
        async_copy16(Ag + rstep + k0, ldsA1);
        async_copy16(Bg + k0,         ldsB0);
        async_copy16(Bg + rstep + k0, ldsB1);
        __syncthreads();                    // drains vmcnt -> tiles visible
        bf16x8 af[4], bfr[4];
#pragma unroll
        for (int mt = 0; mt < 4; ++mt)
            af[mt] = *(const bf16x8*)&As[(wm + mt * 16 + fm) * 32 + slot];
#pragma unroll
        for (int nt = 0; nt < 4; ++nt)
            bfr[nt] = *(const bf16x8*)&Bs[(wn + nt * 16 + fm) * 32 + slot];
#pragma unroll
        for (int mt = 0; mt < 4; ++mt)
#pragma unroll
            for (int nt = 0; nt < 4; ++nt)
                acc[mt][nt] = __builtin_amdgcn_mfma_f32_16x16x32_bf16(
                    af[mt], bfr[nt], acc[mt][nt], 0, 0, 0);
    }

    // epilogue — C/D layout: col = lane&15, row = (lane>>4)*4 + reg
    const int cn0 = n0 + wn + fm;
    int cols[4]; float bi[4];
#pragma unroll
    for (int nt = 0; nt < 4; ++nt) {
        const int c = cn0 + nt * 16;
        cols[nt] = c;
        if (EPI == EPI_SPLIT)
            bi[nt] = (c < 512) ? a.bias0[c] : (c < 768) ? a.bias1[c - 512] : a.bias2[c - 768];
        else
            bi[nt] = a.bias0[c];
    }
#pragma unroll
    for (int mt = 0; mt < 4; ++mt) {
#pragma unroll
        for (int r = 0; r < 4; ++r) {
            const int row = m0 + wm + mt * 16 + fq * 4 + r;
            if (row >= a.M) continue;
            const size_t ro = (size_t)row;
            const float* srcres = (EPI == EPI_RESID_SRC)
                                  ? src_row(row, a.s0, a.s1, a.s2, a.s3) : nullptr;
#pragma unroll
            for (int nt = 0; nt < 4; ++nt) {
                float v = acc[mt][nt][r] + bi[nt];
                const int c = cols[nt];
                if (EPI == EPI_SPLIT) {
                    if (c < 512)      ((unsigned short*)a.out0)[ro * 512 + c]        = f2bf(v);
                    else if (c < 768) a.out1[ro * 256 + (c - 512)]                   = f2bf(v);
                    else              a.out2[ro * 128 + (c - 768)]                   = f2bf(v);
                } else if (EPI == EPI_RESID_SRC) {
                    v += srcres[c];
                    ((unsigned short*)a.out0)[ro * 512 + c] = f2bf(v);
                } else if (EPI == EPI_RELU) {
                    v = fmaxf(v, 0.f);
                    ((unsigned short*)a.out0)[ro * 2048 + c] = f2bf(v);
                } else { // EPI_RESID_SCATTER
                    v += bf2f(a.residb[ro * 512 + c]);
                    ((float*)a.out0)[(size_t)permute_row(row) * 512 + c] = v;
                }
            }
        }
    }
}

// ---------------------------------------------------------------------------
// fp32 [K,N] -> bf16 [N,K] transpose-convert (weights repacked every call)
// ---------------------------------------------------------------------------
__global__ __launch_bounds__(256) void transpose_bf16(
    const float* __restrict__ W, unsigned short* __restrict__ Wt, int K, int N)
{
    __shared__ unsigned short t[32][33];
    const int tx = threadIdx.x & 31, ty = threadIdx.x >> 5;
    const int nb = blockIdx.x * 32, kb = blockIdx.y * 32;
#pragma unroll
    for (int j = 0; j < 32; j += 8)
        t[ty + j][tx] = f2bf(W[(size_t)(kb + ty + j) * N + nb + tx]);
    __syncthreads();
#pragma unroll
    for (int j = 0; j < 32; j += 8)
        Wt[(size_t)(nb + ty + j) * K + kb + tx] = t[tx][ty + j];
}

// concat 4 src scales -> Qb bf16 [TPAD,512] (rows >= TTOT left as-is)
__global__ __launch_bounds__(256) void concat_q_bf16(
    const float* __restrict__ s0, const float* __restrict__ s1,
    const float* __restrict__ s2, const float* __restrict__ s3,
    unsigned short* __restrict__ Qb)
{
    const int gid = blockIdx.x * 256 + threadIdx.x;   // over TTOT*128
    if (gid >= TTOT * 128) return;
    const int e = gid * 4;
    const int row = e >> 9, col = e & 511;
    const float* sr = src_row(row, s0, s1, s2, s3);
    const float4 v = *(const float4*)(sr + col);
    ushort4 o;
    o.x = f2bf(v.x); o.y = f2bf(v.y); o.z = f2bf(v.z); o.w = f2bf(v.w);
    *(ushort4*)(Qb + (size_t)row * 512 + col) = o;
}

// ---------------------------------------------------------------------------
// deformable sampling: one wave per (token, head); lane = channel
// ---------------------------------------------------------------------------
__global__ __launch_bounds__(256) void sample_attn(
    const unsigned short* __restrict__ Vp, const unsigned short* __restrict__ OFFB,
    const unsigned short* __restrict__ ATT,
    const float* __restrict__ rf0, const float* __restrict__ rf1,
    const float* __restrict__ rf2, const float* __restrict__ rf3,
    unsigned short* __restrict__ ACCb)
{
    int wid = (blockIdx.x << 2) + (threadIdx.x >> 6);
    if (wid >= TTOT * 8) return;
    const int lane = threadIdx.x & 63;
    const int t = wid >> 3;
    const int h = wid & 7;

    int soff, area;
    const float* rp;
    if (t < 12544)      { soff = 0;     area = 3136; rp = rf0 + (size_t)t * 2; }
    else if (t < 15680) { soff = 12544; area = 784;  rp = rf1 + (size_t)(t - 12544) * 2; }
    else if (t < 16464) { soff = 15680; area = 196;  rp = rf2 + (size_t)(t - 15680) * 2; }
    else                { soff = 16464; area = 49;   rp = rf3 + (size_t)(t - 16464) * 2; }
    const int b = (t - soff) / area;

    // softmax over the 16 (level,k) logits of this head
    const unsigned short* at = ATT + (size_t)t * 128 + h * 16;
    float wv[16];
    float mx = -1e30f;
#pragma unroll
    for (int j = 0; j < 16; ++j) { wv[j] = bf2f(at[j]); mx = fmaxf(mx, wv[j]); }
    float sum = 0.f;
#pragma unroll
    for (int j = 0; j < 16; ++j) { wv[j] = __expf(wv[j] - mx); sum += wv[j]; }
    const float inv = 1.f / sum;

    const float rx = rp[0];
    const float ry = rp[1];
    const unsigned short* ob = OFFB + (size_t)t * 256 + h * 32;

    float acc = 0.f;
#pragma unroll
    for (int li = 0; li < 4; ++li) {
        const int wl = (li == 0) ? 56 : (li == 1) ? 28 : (li == 2) ? 14 : 7;
        const int hl = wl;
        const int vtok0 = ((li == 0) ? 0 : (li == 1) ? 12544 : (li == 2) ? 15680 : 16464)
                          + b * wl * hl;
        const unsigned short* vb = Vp + (size_t)vtok0 * 512 + h * 64 + lane;
#pragma unroll
        for (int k = 0; k < 4; ++k) {
            const float ox = bf2f(ob[(li * 4 + k) * 2 + 0]);
            const float oy = bf2f(ob[(li * 4 + k) * 2 + 1]);
            const float x = (rx + ox / (float)wl) * (float)wl - 0.5f;
            const float y = (ry + oy / (float)hl) * (float)hl - 0.5f;
            const float x0f = floorf(x), y0f = floorf(y);
            const float wx1 = x - x0f, wx0 = 1.f - wx1;
            const float wy1 = y - y0f, wy0 = 1.f - wy1;
            const int x0 = (int)x0f, y0 = (int)y0f;
            const int x1 = x0 + 1, y1 = y0 + 1;
            const bool vx0 = (x0 >= 0) & (x0 < wl);
            const bool vx1 = (x1 >= 0) & (x1 < wl);
            const bool vy0 = (y0 >= 0) & (y0 < hl);
            const bool vy1 = (y1 >= 0) & (y1 < hl);
            float sv = 0.f;
            if (vx0 & vy0) sv += wx0 * wy0 * bf2f(vb[(size_t)(y0 * wl + x0) * 512]);
            if (vx1 & vy0) sv += wx1 * wy0 * bf2f(vb[(size_t)(y0 * wl + x1) * 512]);
            if (vx0 & vy1) sv += wx0 * wy1 * bf2f(vb[(size_t)(y1 * wl + x0) * 512]);
            if (vx1 & vy1) sv += wx1 * wy1 * bf2f(vb[(size_t)(y1 * wl + x1) * 512]);
            acc += (wv[li * 4 + k] * inv) * sv;
        }
    }
    ACCb[(size_t)t * 512 + h * 64 + lane] = f2bf(acc);
}

// in-place layernorm on bf16 rows of 512 (fp32 stats)
__global__ __launch_bounds__(256) void ln_bf16(
    unsigned short* __restrict__ X, const float* __restrict__ g, const float* __restrict__ be)
{
    const int row = blockIdx.x;
    unsigned short* xr = X + (size_t)row * 512;
    const int tid = threadIdx.x;
    float v0 = bf2f(xr[tid]);
    float v1 = bf2f(xr[tid + 256]);
    float s = v0 + v1;
    float ss = v0 * v0 + v1 * v1;
#pragma unroll
    for (int o = 32; o > 0; o >>= 1) {
        s += __shfl_down(s, o, 64);
        ss += __shfl_down(ss, o, 64);
    }
    __shared__ float sm[4], sm2[4];
    const int w = tid >> 6;
    if ((tid & 63) == 0) { sm[w] = s; sm2[w] = ss; }
    __syncthreads();
    if (tid == 0) {
        sm[0] = sm[0] + sm[1] + sm[2] + sm[3];
        sm2[0] = sm2[0] + sm2[1] + sm2[2] + sm2[3];
    }
    __syncthreads();
    const float mu = sm[0] * (1.f / 512.f);
    const float var = sm2[0] * (1.f / 512.f) - mu * mu;
    const float rs = rsqrtf(var + 1e-5f);
    xr[tid]       = f2bf((v0 - mu) * rs * g[tid]       + be[tid]);
    xr[tid + 256] = f2bf((v1 - mu) * rs * g[tid + 256] + be[tid + 256]);
}

// in-place fp32 layernorm (final, on d_out)
__global__ __launch_bounds__(256) void ln_f32(
    float* __restrict__ X, const float* __restrict__ g, const float* __restrict__ be)
{
    const int row = blockIdx.x;
    float* xr = X + (size_t)row * 512;
    const int tid = threadIdx.x;
    float v0 = xr[tid];
    float v1 = xr[tid + 256];
    float s = v0 + v1;
    float ss = v0 * v0 + v1 * v1;
#pragma unroll
    for (int o = 32; o > 0; o >>= 1) {
        s += __shfl_down(s, o, 64);
        ss += __shfl_down(ss, o, 64);
    }
    __shared__ float sm[4], sm2[4];
    const int w = tid >> 6;
    if ((tid & 63) == 0) { sm[w] = s; sm2[w] = ss; }
    __syncthreads();
    if (tid == 0) {
        sm[0] = sm[0] + sm[1] + sm[2] + sm[3];
        sm2[0] = sm2[0] + sm2[1] + sm2[2] + sm2[3];
    }
    __syncthreads();
    const float mu = sm[0] * (1.f / 512.f);
    const float var = sm2[0] * (1.f / 512.f) - mu * mu;
    const float rs = rsqrtf(var + 1e-5f);
    xr[tid]       = (v0 - mu) * rs * g[tid]       + be[tid];
    xr[tid + 256] = (v1 - mu) * rs * g[tid + 256] + be[tid + 256];
}

extern "C" void kernel_launch(void* const* d_in, const int* in_sizes, int n_in,
                              void* d_out, int out_size, void* d_ws, size_t ws_size,
                              hipStream_t stream)
{
    const float* src[4] = { (const float*)d_in[0], (const float*)d_in[2],
                            (const float*)d_in[4], (const float*)d_in[6] };
    const float* ref[4] = { (const float*)d_in[1], (const float*)d_in[3],
                            (const float*)d_in[5], (const float*)d_in[7] };
    const float* Wv    = (const float*)d_in[8];
    const float* bv    = (const float*)d_in[9];
    const float* Woff  = (const float*)d_in[10];
    const float* boff  = (const float*)d_in[11];
    const float* Wattn = (const float*)d_in[12];
    const float* battn = (const float*)d_in[13];
    const float* Wo    = (const float*)d_in[14];
    const float* bo    = (const float*)d_in[15];
    const float* W1    = (const float*)d_in[16];
    const float* b1    = (const float*)d_in[17];
    const float* W2    = (const float*)d_in[18];
    const float* b2    = (const float*)d_in[19];
    const float* g1    = (const float*)d_in[20];
    const float* be1   = (const float*)d_in[21];
    const float* g2    = (const float*)d_in[22];
    const float* be2   = (const float*)d_in[23];

    // workspace layout (bf16 == unsigned short), ~156 MB total
    unsigned short* w    = (unsigned short*)d_ws;
    unsigned short* Qb   = w;                              // [TPAD,512]
    unsigned short* Vp   = Qb   + (size_t)TPAD * 512;      // [TPAD,512]
    unsigned short* OFFB = Vp   + (size_t)TPAD * 512;      // [TPAD,256]
    unsigned short* ATT  = OFFB + (size_t)TPAD * 256;      // [TPAD,128]
    unsigned short* ACCb = ATT  + (size_t)TPAD * 128;      // [TPAD,512]
    unsigned short* X1b  = ACCb + (size_t)TPAD * 512;      // [TPAD,512]
    unsigned short* Fb   = X1b  + (size_t)TPAD * 512;      // [TPAD,2048]
    unsigned short* Wcat = Fb   + (size_t)TPAD * 2048;     // [896,512]  (Wv|Woff|Wattn)^T
    unsigned short* Wot  = Wcat + (size_t)896 * 512;       // [512,512]
    unsigned short* W1t  = Wot  + (size_t)512 * 512;       // [2048,512]
    unsigned short* W2t  = W1t  + (size_t)2048 * 512;      // [512,2048]

    const dim3 blk(256);

    // repack weights -> bf16 transposed (every call; ws is re-poisoned)
    transpose_bf16<<<dim3(16, 16), blk, 0, stream>>>(Wv,    Wcat,                    512, 512);
    transpose_bf16<<<dim3(8,  16), blk, 0, stream>>>(Woff,  Wcat + (size_t)512*512,  512, 256);
    transpose_bf16<<<dim3(4,  16), blk, 0, stream>>>(Wattn, Wcat + (size_t)768*512,  512, 128);
    transpose_bf16<<<dim3(16, 16), blk, 0, stream>>>(Wo,    Wot,                     512, 512);
    transpose_bf16<<<dim3(64, 16), blk, 0, stream>>>(W1,    W1t,                     512, 2048);
    transpose_bf16<<<dim3(16, 64), blk, 0, stream>>>(W2,    W2t,                     2048, 512);
    concat_q_bf16<<<dim3(8330), blk, 0, stream>>>(src[0], src[1], src[2], src[3], Qb);

    // fused V/off/attn projection: [T,512] @ [512,896]
    GemmArgs a1 = {};
    a1.A = Qb; a1.Bt = Wcat; a1.bias0 = bv; a1.bias1 = boff; a1.bias2 = battn;
    a1.out0 = Vp; a1.out1 = OFFB; a1.out2 = ATT; a1.M = TTOT; a1.N = 896; a1.Kd = 512;
    gemm_mfma<EPI_SPLIT><<<dim3(7, 131), blk, 0, stream>>>(a1);

    sample_attn<<<dim3(33320), blk, 0, stream>>>(Vp, OFFB, ATT,
                                                 ref[0], ref[1], ref[2], ref[3], ACCb);

    // output projection + residual(q from srcs)
    GemmArgs a2 = {};
    a2.A = ACCb; a2.Bt = Wot; a2.bias0 = bo;
    a2.s0 = src[0]; a2.s1 = src[1]; a2.s2 = src[2]; a2.s3 = src[3];
    a2.out0 = X1b; a2.M = TTOT; a2.N = 512; a2.Kd = 512;
    gemm_mfma<EPI_RESID_SRC><<<dim3(4, 131), blk, 0, stream>>>(a2);

    ln_bf16<<<dim3(TTOT), blk, 0, stream>>>(X1b, g1, be1);

    // FFN up + relu
    GemmArgs a3 = {};
    a3.A = X1b; a3.Bt = W1t; a3.bias0 = b1;
    a3.out0 = Fb; a3.M = TTOT; a3.N = 2048; a3.Kd = 512;
    gemm_mfma<EPI_RELU><<<dim3(16, 131), blk, 0, stream>>>(a3);

    // FFN down + residual(x) + scatter into d_out layout
    GemmArgs a4 = {};
    a4.A = Fb; a4.Bt = W2t; a4.bias0 = b2; a4.residb = X1b;
    a4.out0 = d_out; a4.M = TTOT; a4.N = 512; a4.Kd = 2048;
    gemm_mfma<EPI_RESID_SCATTER><<<dim3(4, 131), blk, 0, stream>>>(a4);

    ln_f32<<<dim3(TTOT), blk, 0, stream>>>((float*)d_out, g2, be2);
}

// Round 3
// 473.155 us; speedup vs baseline: 4.4493x; 1.5020x over previous
//
#include <hip/hip_runtime.h>
#include <math.h>

// ---------------------------------------------------------------------------
// DETR deformable-transformer encoder layer, MI355X — bf16 MFMA version.
// D=512, H=8, DFF=2048, K=4, S=4, DH=64, B=4
// token counts per scale (incl. batch): 12544, 3136, 784, 196 ; T=16660
// ---------------------------------------------------------------------------

#define TTOT 16660
#define TPAD 16768   // 131 * 128
#define LQTOT 4165

typedef __attribute__((ext_vector_type(8))) short bf16x8;
typedef __attribute__((ext_vector_type(4))) float f32x4;

typedef __attribute__((address_space(1))) const unsigned int g_u32;
typedef __attribute__((address_space(3))) unsigned int l_u32;

__device__ __forceinline__ unsigned short f2bf(float f) {
    unsigned u = __builtin_bit_cast(unsigned, f);
    u += 0x7fffu + ((u >> 16) & 1u);
    return (unsigned short)(u >> 16);
}
__device__ __forceinline__ float bf2f(unsigned short s) {
    unsigned u = ((unsigned)s) << 16;
    return __builtin_bit_cast(float, u);
}

// token row -> row in d_out ([B, 4165, 512], scales concatenated per batch)
__device__ __forceinline__ int permute_row(int t) {
    int off, area, qoff;
    if (t < 12544)      { off = 0;     area = 3136; qoff = 0;    }
    else if (t < 15680) { off = 12544; area = 784;  qoff = 3136; }
    else if (t < 16464) { off = 15680; area = 196;  qoff = 3920; }
    else                { off = 16464; area = 49;   qoff = 4116; }
    int rel = t - off;
    int b = rel / area;
    int pos = rel - b * area;
    return b * LQTOT + qoff + pos;
}

// token row -> fp32 row pointer inside the 4 concatenated src arrays
__device__ __forceinline__ const float* src_row(int row, const float* s0, const float* s1,
                                                const float* s2, const float* s3) {
    if (row < 12544) return s0 + (size_t)row * 512;
    if (row < 15680) return s1 + (size_t)(row - 12544) * 512;
    if (row < 16464) return s2 + (size_t)(row - 15680) * 512;
    return s3 + (size_t)(row - 16464) * 512;
}

__device__ __forceinline__ void async_copy16(const unsigned short* g, unsigned short* lds_wave_uniform) {
    __builtin_amdgcn_global_load_lds((g_u32*)g, (l_u32*)lds_wave_uniform, 16, 0, 0);
}

// ---------------------------------------------------------------------------
// bf16 MFMA GEMM: C = A[M,Kd] @ (Bt[N,Kd])^T (+bias)(+epilogue)
// 128x128 tile, BK=32, 256 threads = 4 waves (2x2 of 64x64), 16x16x32 MFMA.
// ---------------------------------------------------------------------------
enum { EPI_SPLIT = 0, EPI_RESID_SRC = 1, EPI_RELU = 2, EPI_RESID_SCATTER = 3 };

struct GemmArgs {
    const unsigned short* A;    // [Mpad, Kd] bf16
    const unsigned short* Bt;   // [N, Kd]   bf16 (W^T)
    const float* bias0; const float* bias1; const float* bias2;
    const unsigned short* residb;   // bf16 residual (scatter epi)
    const float* s0; const float* s1; const float* s2; const float* s3; // fp32 resid gather
    void* out0; unsigned short* out1; unsigned short* out2;
    int M, N, Kd;
};

template <int EPI>
__global__ __launch_bounds__(256) void gemm_mfma(GemmArgs a)
{
    __shared__ unsigned short As[128 * 32];
    __shared__ unsigned short Bs[128 * 32];
    const int tid  = threadIdx.x;
    const int wave = tid >> 6;
    const int lane = tid & 63;
    const int m0 = blockIdx.y * 128;
    const int n0 = blockIdx.x * 128;

    const int srow = tid >> 2;
    const int kg   = (tid & 3) ^ ((tid >> 3) & 3);
    const unsigned short* Ag = a.A  + (size_t)(m0 + srow) * a.Kd + kg * 8;
    const unsigned short* Bg = a.Bt + (size_t)(n0 + srow) * a.Kd + kg * 8;
    const size_t rstep = (size_t)64 * a.Kd;
    unsigned short* ldsA0 = As + wave * 512;
    unsigned short* ldsA1 = As + 2048 + wave * 512;
    unsigned short* ldsB0 = Bs + wave * 512;
    unsigned short* ldsB1 = Bs + 2048 + wave * 512;

    const int wm = (wave >> 1) << 6;
    const int wn = (wave & 1) << 6;
    const int fm = lane & 15;
    const int fq = lane >> 4;
    const int slot = (fq ^ ((fm >> 1) & 3)) << 3;

    const f32x4 fzero = {0.f, 0.f, 0.f, 0.f};
    f32x4 acc[4][4];
#pragma unroll
    for (int i = 0; i < 4; ++i)
#pragma unroll
        for (int j = 0; j < 4; ++j) acc[i][j] = fzero;

    for (int k0 = 0; k0 < a.Kd; k0 += 32) {
        __syncthreads();
        async_copy16(Ag + k0,         ldsA0);
        async_copy16(Ag + rstep + k0, ldsA1);
        async_copy16(Bg + k0,         ldsB0);
        async_copy16(Bg + rstep + k0, ldsB1);
        __syncthreads();
        bf16x8 af[4], bfr[4];
#pragma unroll
        for (int mt = 0; mt < 4; ++mt)
            af[mt] = *(const bf16x8*)&As[(wm + mt * 16 + fm) * 32 + slot];
#pragma unroll
        for (int nt = 0; nt < 4; ++nt)
            bfr[nt] = *(const bf16x8*)&Bs[(wn + nt * 16 + fm) * 32 + slot];
#pragma unroll
        for (int mt = 0; mt < 4; ++mt)
#pragma unroll
            for (int nt = 0; nt < 4; ++nt)
                acc[mt][nt] = __builtin_amdgcn_mfma_f32_16x16x32_bf16(
                    af[mt], bfr[nt], acc[mt][nt], 0, 0, 0);
    }

    // epilogue — C/D layout: col = lane&15, row = (lane>>4)*4 + reg
    const int cn0 = n0 + wn + fm;
    int cols[4]; float bi[4];
#pragma unroll
    for (int nt = 0; nt < 4; ++nt) {
        const int c = cn0 + nt * 16;
        cols[nt] = c;
        if (EPI == EPI_SPLIT)
            bi[nt] = (c < 512) ? a.bias0[c] : (c < 768) ? a.bias1[c - 512] : a.bias2[c - 768];
        else
            bi[nt] = a.bias0[c];
    }
#pragma unroll
    for (int mt = 0; mt < 4; ++mt) {
#pragma unroll
        for (int r = 0; r < 4; ++r) {
            const int row = m0 + wm + mt * 16 + fq * 4 + r;
            if (row >= a.M) continue;
            const size_t ro = (size_t)row;
            const float* srcres = (EPI == EPI_RESID_SRC)
                                  ? src_row(row, a.s0, a.s1, a.s2, a.s3) : nullptr;
#pragma unroll
            for (int nt = 0; nt < 4; ++nt) {
                float v = acc[mt][nt][r] + bi[nt];
                const int c = cols[nt];
                if (EPI == EPI_SPLIT) {
                    if (c < 512)      ((unsigned short*)a.out0)[ro * 512 + c]        = f2bf(v);
                    else if (c < 768) a.out1[ro * 256 + (c - 512)]                   = f2bf(v);
                    else              a.out2[ro * 128 + (c - 768)]                   = f2bf(v);
                } else if (EPI == EPI_RESID_SRC) {
                    v += srcres[c];
                    ((unsigned short*)a.out0)[ro * 512 + c] = f2bf(v);
                } else if (EPI == EPI_RELU) {
                    v = fmaxf(v, 0.f);
                    ((unsigned short*)a.out0)[ro * 2048 + c] = f2bf(v);
                } else { // EPI_RESID_SCATTER
                    v += bf2f(a.residb[ro * 512 + c]);
                    ((float*)a.out0)[(size_t)permute_row(row) * 512 + c] = v;
                }
            }
        }
    }
}

// ---------------------------------------------------------------------------
// fp32 [K,N] -> bf16 [N,K] transpose-convert
// ---------------------------------------------------------------------------
__global__ __launch_bounds__(256) void transpose_bf16(
    const float* __restrict__ W, unsigned short* __restrict__ Wt, int K, int N)
{
    __shared__ unsigned short t[32][33];
    const int tx = threadIdx.x & 31, ty = threadIdx.x >> 5;
    const int nb = blockIdx.x * 32, kb = blockIdx.y * 32;
#pragma unroll
    for (int j = 0; j < 32; j += 8)
        t[ty + j][tx] = f2bf(W[(size_t)(kb + ty + j) * N + nb + tx]);
    __syncthreads();
#pragma unroll
    for (int j = 0; j < 32; j += 8)
        Wt[(size_t)(nb + ty + j) * K + kb + tx] = t[tx][ty + j];
}

// concat 4 src scales -> Qb bf16 [TPAD,512]
__global__ __launch_bounds__(256) void concat_q_bf16(
    const float* __restrict__ s0, const float* __restrict__ s1,
    const float* __restrict__ s2, const float* __restrict__ s3,
    unsigned short* __restrict__ Qb)
{
    const int gid = blockIdx.x * 256 + threadIdx.x;   // over TTOT*128
    if (gid >= TTOT * 128) return;
    const int e = gid * 4;
    const int row = e >> 9, col = e & 511;
    const float* sr = src_row(row, s0, s1, s2, s3);
    const float4 v = *(const float4*)(sr + col);
    ushort4 o;
    o.x = f2bf(v.x); o.y = f2bf(v.y); o.z = f2bf(v.z); o.w = f2bf(v.w);
    *(ushort4*)(Qb + (size_t)row * 512 + col) = o;
}

// ---------------------------------------------------------------------------
// deformable sampling v2: one wave per (token, head).
// Phase 1: lanes 0-15 each own one (level,k) sample — softmax via 16-lane
//   shuffles, coords (division algebraically removed), clamped indices and
//   validity-zeroed weights -> LDS meta (int4 idx, float4 w).
// Phase 2: lane = channel; 64 unconditional coalesced bf16 gathers + fma,
//   meta read broadcast from LDS; softmax denom applied once at the end.
// ---------------------------------------------------------------------------
__global__ __launch_bounds__(256) void sample_attn(
    const unsigned short* __restrict__ Vp, const unsigned short* __restrict__ OFFB,
    const unsigned short* __restrict__ ATT,
    const float* __restrict__ rf0, const float* __restrict__ rf1,
    const float* __restrict__ rf2, const float* __restrict__ rf3,
    unsigned short* __restrict__ ACCb)
{
    __shared__ int   midx[4][16][4];
    __shared__ float mw[4][16][4];
    const int wave = threadIdx.x >> 6;
    const int lane = threadIdx.x & 63;
    const int wid  = (blockIdx.x << 2) + wave;   // grid exactly TTOT*8/4
    const int t = wid >> 3;
    const int h = wid & 7;

    int soff, area;
    const float* rp;
    if (t < 12544)      { soff = 0;     area = 3136; rp = rf0 + (size_t)t * 2; }
    else if (t < 15680) { soff = 12544; area = 784;  rp = rf1 + (size_t)(t - 12544) * 2; }
    else if (t < 16464) { soff = 15680; area = 196;  rp = rf2 + (size_t)(t - 15680) * 2; }
    else                { soff = 16464; area = 49;   rp = rf3 + (size_t)(t - 16464) * 2; }
    const int b = (t - soff) / area;

    float sumv = 0.f;
    if (lane < 16) {
        const int s = lane;
        const int li = s >> 2;
        // logit + 16-wide softmax (denominator deferred)
        float logit = bf2f(ATT[(size_t)t * 128 + h * 16 + s]);
        float mx = logit;
#pragma unroll
        for (int o = 8; o > 0; o >>= 1) mx = fmaxf(mx, __shfl_xor(mx, o, 16));
        float e = __expf(logit - mx);
        sumv = e;
#pragma unroll
        for (int o = 8; o > 0; o >>= 1) sumv += __shfl_xor(sumv, o, 16);

        // coords: (rx + ox/wl)*wl - 0.5 == rx*wl + ox - 0.5
        const int wl = 56 >> li;
        const int lvlbase = (li == 0) ? 0 : (li == 1) ? 12544 : (li == 2) ? 15680 : 16464;
        const int base = lvlbase + b * wl * wl;
        const float rx = rp[0], ry = rp[1];
        const float ox = bf2f(OFFB[(size_t)t * 256 + h * 32 + s * 2 + 0]);
        const float oy = bf2f(OFFB[(size_t)t * 256 + h * 32 + s * 2 + 1]);
        const float x = rx * (float)wl + ox - 0.5f;
        const float y = ry * (float)wl + oy - 0.5f;
        const float x0f = floorf(x), y0f = floorf(y);
        const float wx1 = x - x0f, wx0 = 1.f - wx1;
        const float wy1 = y - y0f, wy0 = 1.f - wy1;
        const int x0 = (int)x0f, y0 = (int)y0f;
        const int x1 = x0 + 1, y1 = y0 + 1;
        const int xc0 = min(max(x0, 0), wl - 1), xc1 = min(max(x1, 0), wl - 1);
        const int yc0 = min(max(y0, 0), wl - 1), yc1 = min(max(y1, 0), wl - 1);
        const float fx0 = (x0 >= 0 && x0 < wl) ? 1.f : 0.f;
        const float fx1 = (x1 >= 0 && x1 < wl) ? 1.f : 0.f;
        const float fy0 = (y0 >= 0 && y0 < wl) ? 1.f : 0.f;
        const float fy1 = (y1 >= 0 && y1 < wl) ? 1.f : 0.f;
        const int hb = h * 64;
        midx[wave][s][0] = (base + yc0 * wl + xc0) * 512 + hb;
        midx[wave][s][1] = (base + yc0 * wl + xc1) * 512 + hb;
        midx[wave][s][2] = (base + yc1 * wl + xc0) * 512 + hb;
        midx[wave][s][3] = (base + yc1 * wl + xc1) * 512 + hb;
        mw[wave][s][0] = wx0 * wy0 * fx0 * fy0 * e;
        mw[wave][s][1] = wx1 * wy0 * fx1 * fy0 * e;
        mw[wave][s][2] = wx0 * wy1 * fx0 * fy1 * e;
        mw[wave][s][3] = wx1 * wy1 * fx1 * fy1 * e;
    }
    __syncthreads();
    const float inv = 1.f / __shfl(sumv, 0, 64);

    float acc = 0.f;
#pragma unroll
    for (int s = 0; s < 16; ++s) {
        const int4  I = *(const int4*)&midx[wave][s][0];
        const float4 W = *(const float4*)&mw[wave][s][0];
        acc += W.x * bf2f(Vp[(size_t)(I.x + lane)]);
        acc += W.y * bf2f(Vp[(size_t)(I.y + lane)]);
        acc += W.z * bf2f(Vp[(size_t)(I.z + lane)]);
        acc += W.w * bf2f(Vp[(size_t)(I.w + lane)]);
    }
    ACCb[(size_t)t * 512 + h * 64 + lane] = f2bf(acc * inv);
}

// in-place layernorm on bf16 rows of 512 (fp32 stats)
__global__ __launch_bounds__(256) void ln_bf16(
    unsigned short* __restrict__ X, const float* __restrict__ g, const float* __restrict__ be)
{
    const int row = blockIdx.x;
    unsigned short* xr = X + (size_t)row * 512;
    const int tid = threadIdx.x;
    float v0 = bf2f(xr[tid]);
    float v1 = bf2f(xr[tid + 256]);
    float s = v0 + v1;
    float ss = v0 * v0 + v1 * v1;
#pragma unroll
    for (int o = 32; o > 0; o >>= 1) {
        s += __shfl_down(s, o, 64);
        ss += __shfl_down(ss, o, 64);
    }
    __shared__ float sm[4], sm2[4];
    const int w = tid >> 6;
    if ((tid & 63) == 0) { sm[w] = s; sm2[w] = ss; }
    __syncthreads();
    if (tid == 0) {
        sm[0] = sm[0] + sm[1] + sm[2] + sm[3];
        sm2[0] = sm2[0] + sm2[1] + sm2[2] + sm2[3];
    }
    __syncthreads();
    const float mu = sm[0] * (1.f / 512.f);
    const float var = sm2[0] * (1.f / 512.f) - mu * mu;
    const float rs = rsqrtf(var + 1e-5f);
    xr[tid]       = f2bf((v0 - mu) * rs * g[tid]       + be[tid]);
    xr[tid + 256] = f2bf((v1 - mu) * rs * g[tid + 256] + be[tid + 256]);
}

// in-place fp32 layernorm (final, on d_out)
__global__ __launch_bounds__(256) void ln_f32(
    float* __restrict__ X, const float* __restrict__ g, const float* __restrict__ be)
{
    const int row = blockIdx.x;
    float* xr = X + (size_t)row * 512;
    const int tid = threadIdx.x;
    float v0 = xr[tid];
    float v1 = xr[tid + 256];
    float s = v0 + v1;
    float ss = v0 * v0 + v1 * v1;
#pragma unroll
    for (int o = 32; o > 0; o >>= 1) {
        s += __shfl_down(s, o, 64);
        ss += __shfl_down(ss, o, 64);
    }
    __shared__ float sm[4], sm2[4];
    const int w = tid >> 6;
    if ((tid & 63) == 0) { sm[w] = s; sm2[w] = ss; }
    __syncthreads();
    if (tid == 0) {
        sm[0] = sm[0] + sm[1] + sm[2] + sm[3];
        sm2[0] = sm2[0] + sm2[1] + sm2[2] + sm2[3];
    }
    __syncthreads();
    const float mu = sm[0] * (1.f / 512.f);
    const float var = sm2[0] * (1.f / 512.f) - mu * mu;
    const float rs = rsqrtf(var + 1e-5f);
    xr[tid]       = (v0 - mu) * rs * g[tid]       + be[tid];
    xr[tid + 256] = (v1 - mu) * rs * g[tid + 256] + be[tid + 256];
}

extern "C" void kernel_launch(void* const* d_in, const int* in_sizes, int n_in,
                              void* d_out, int out_size, void* d_ws, size_t ws_size,
                              hipStream_t stream)
{
    const float* src[4] = { (const float*)d_in[0], (const float*)d_in[2],
                            (const float*)d_in[4], (const float*)d_in[6] };
    const float* ref[4] = { (const float*)d_in[1], (const float*)d_in[3],
                            (const float*)d_in[5], (const float*)d_in[7] };
    const float* Wv    = (const float*)d_in[8];
    const float* bv    = (const float*)d_in[9];
    const float* Woff  = (const float*)d_in[10];
    const float* boff  = (const float*)d_in[11];
    const float* Wattn = (const float*)d_in[12];
    const float* battn = (const float*)d_in[13];
    const float* Wo    = (const float*)d_in[14];
    const float* bo    = (const float*)d_in[15];
    const float* W1    = (const float*)d_in[16];
    const float* b1    = (const float*)d_in[17];
    const float* W2    = (const float*)d_in[18];
    const float* b2    = (const float*)d_in[19];
    const float* g1    = (const float*)d_in[20];
    const float* be1   = (const float*)d_in[21];
    const float* g2    = (const float*)d_in[22];
    const float* be2   = (const float*)d_in[23];

    // workspace layout (bf16 == unsigned short)
    unsigned short* w    = (unsigned short*)d_ws;
    unsigned short* Qb   = w;                              // [TPAD,512]
    unsigned short* Vp   = Qb   + (size_t)TPAD * 512;      // [TPAD,512]
    unsigned short* OFFB = Vp   + (size_t)TPAD * 512;      // [TPAD,256]
    unsigned short* ATT  = OFFB + (size_t)TPAD * 256;      // [TPAD,128]
    unsigned short* ACCb = ATT  + (size_t)TPAD * 128;      // [TPAD,512]
    unsigned short* X1b  = ACCb + (size_t)TPAD * 512;      // [TPAD,512]
    unsigned short* Fb   = X1b  + (size_t)TPAD * 512;      // [TPAD,2048]
    unsigned short* Wcat = Fb   + (size_t)TPAD * 2048;     // [896,512]
    unsigned short* Wot  = Wcat + (size_t)896 * 512;       // [512,512]
    unsigned short* W1t  = Wot  + (size_t)512 * 512;       // [2048,512]
    unsigned short* W2t  = W1t  + (size_t)2048 * 512;      // [512,2048]

    const dim3 blk(256);

    transpose_bf16<<<dim3(16, 16), blk, 0, stream>>>(Wv,    Wcat,                    512, 512);
    transpose_bf16<<<dim3(8,  16), blk, 0, stream>>>(Woff,  Wcat + (size_t)512*512,  512, 256);
    transpose_bf16<<<dim3(4,  16), blk, 0, stream>>>(Wattn, Wcat + (size_t)768*512,  512, 128);
    transpose_bf16<<<dim3(16, 16), blk, 0, stream>>>(Wo,    Wot,                     512, 512);
    transpose_bf16<<<dim3(64, 16), blk, 0, stream>>>(W1,    W1t,                     512, 2048);
    transpose_bf16<<<dim3(16, 64), blk, 0, stream>>>(W2,    W2t,                     2048, 512);
    concat_q_bf16<<<dim3(8330), blk, 0, stream>>>(src[0], src[1], src[2], src[3], Qb);

    // fused V/off/attn projection: [T,512] @ [512,896]
    GemmArgs a1 = {};
    a1.A = Qb; a1.Bt = Wcat; a1.bias0 = bv; a1.bias1 = boff; a1.bias2 = battn;
    a1.out0 = Vp; a1.out1 = OFFB; a1.out2 = ATT; a1.M = TTOT; a1.N = 896; a1.Kd = 512;
    gemm_mfma<EPI_SPLIT><<<dim3(7, 131), blk, 0, stream>>>(a1);

    sample_attn<<<dim3(33320), blk, 0, stream>>>(Vp, OFFB, ATT,
                                                 ref[0], ref[1], ref[2], ref[3], ACCb);

    // output projection + residual(q from srcs)
    GemmArgs a2 = {};
    a2.A = ACCb; a2.Bt = Wot; a2.bias0 = bo;
    a2.s0 = src[0]; a2.s1 = src[1]; a2.s2 = src[2]; a2.s3 = src[3];
    a2.out0 = X1b; a2.M = TTOT; a2.N = 512; a2.Kd = 512;
    gemm_mfma<EPI_RESID_SRC><<<dim3(4, 131), blk, 0, stream>>>(a2);

    ln_bf16<<<dim3(TTOT), blk, 0, stream>>>(X1b, g1, be1);

    // FFN up + relu
    GemmArgs a3 = {};
    a3.A = X1b; a3.Bt = W1t; a3.bias0 = b1;
    a3.out0 = Fb; a3.M = TTOT; a3.N = 2048; a3.Kd = 512;
    gemm_mfma<EPI_RELU><<<dim3(16, 131), blk, 0, stream>>>(a3);

    // FFN down + residual(x) + scatter into d_out layout
    GemmArgs a4 = {};
    a4.A = Fb; a4.Bt = W2t; a4.bias0 = b2; a4.residb = X1b;
    a4.out0 = d_out; a4.M = TTOT; a4.N = 512; a4.Kd = 2048;
    gemm_mfma<EPI_RESID_SCATTER><<<dim3(4, 131), blk, 0, stream>>>(a4);

    ln_f32<<<dim3(TTOT), blk, 0, stream>>>((float*)d_out, g2, be2);
}

// Round 4
// 423.896 us; speedup vs baseline: 4.9664x; 1.1162x over previous
//
#include <hip/hip_runtime.h>
#include <math.h>

// ---------------------------------------------------------------------------
// DETR deformable-transformer encoder layer, MI355X — bf16 MFMA version.
// D=512, H=8, DFF=2048, K=4, S=4, DH=64, B=4
// token counts per scale (incl. batch): 12544, 3136, 784, 196 ; T=16660
// ---------------------------------------------------------------------------

#define TTOT 16660
#define TPAD 16768   // 131 * 128
#define LQTOT 4165

typedef __attribute__((ext_vector_type(8))) short bf16x8;
typedef __attribute__((ext_vector_type(4))) float f32x4;

typedef __attribute__((address_space(1))) const unsigned int g_u32;
typedef __attribute__((address_space(3))) unsigned int l_u32;

__device__ __forceinline__ unsigned short f2bf(float f) {
    unsigned u = __builtin_bit_cast(unsigned, f);
    u += 0x7fffu + ((u >> 16) & 1u);
    return (unsigned short)(u >> 16);
}
__device__ __forceinline__ float bf2f(unsigned short s) {
    unsigned u = ((unsigned)s) << 16;
    return __builtin_bit_cast(float, u);
}
__device__ __forceinline__ float bflo(unsigned u) {           // low bf16 of dword
    return __builtin_bit_cast(float, u << 16);
}
__device__ __forceinline__ float bfhi(unsigned u) {           // high bf16 of dword
    return __builtin_bit_cast(float, u & 0xffff0000u);
}

// token row -> row in d_out ([B, 4165, 512], scales concatenated per batch)
__device__ __forceinline__ int permute_row(int t) {
    int off, area, qoff;
    if (t < 12544)      { off = 0;     area = 3136; qoff = 0;    }
    else if (t < 15680) { off = 12544; area = 784;  qoff = 3136; }
    else if (t < 16464) { off = 15680; area = 196;  qoff = 3920; }
    else                { off = 16464; area = 49;   qoff = 4116; }
    int rel = t - off;
    int b = rel / area;
    int pos = rel - b * area;
    return b * LQTOT + qoff + pos;
}

// token row -> fp32 row pointer inside the 4 concatenated src arrays
__device__ __forceinline__ const float* src_row(int row, const float* s0, const float* s1,
                                                const float* s2, const float* s3) {
    if (row < 12544) return s0 + (size_t)row * 512;
    if (row < 15680) return s1 + (size_t)(row - 12544) * 512;
    if (row < 16464) return s2 + (size_t)(row - 15680) * 512;
    return s3 + (size_t)(row - 16464) * 512;
}

__device__ __forceinline__ void async_copy16(const unsigned short* g, unsigned short* lds_wave_uniform) {
    __builtin_amdgcn_global_load_lds((g_u32*)g, (l_u32*)lds_wave_uniform, 16, 0, 0);
}

// ---------------------------------------------------------------------------
// bf16 MFMA GEMM: C = A[M,Kd] @ (Bt[N,Kd])^T (+bias)(+epilogue)
// 128x128 tile, BK=32, 256 threads = 4 waves (2x2 of 64x64), 16x16x32 MFMA.
// ---------------------------------------------------------------------------
enum { EPI_SPLIT = 0, EPI_RESID_SRC = 1, EPI_RELU = 2, EPI_RESID_SCATTER = 3 };

struct GemmArgs {
    const unsigned short* A;    // [Mpad, Kd] bf16
    const unsigned short* Bt;   // [N, Kd]   bf16 (W^T)
    const float* bias0; const float* bias1; const float* bias2;
    const unsigned short* residb;   // bf16 residual (scatter epi)
    const float* s0; const float* s1; const float* s2; const float* s3; // fp32 resid gather
    void* out0; unsigned short* out1; unsigned short* out2;
    int M, N, Kd;
};

template <int EPI>
__global__ __launch_bounds__(256) void gemm_mfma(GemmArgs a)
{
    __shared__ unsigned short As[128 * 32];
    __shared__ unsigned short Bs[128 * 32];
    const int tid  = threadIdx.x;
    const int wave = tid >> 6;
    const int lane = tid & 63;
    const int m0 = blockIdx.y * 128;
    const int n0 = blockIdx.x * 128;

    const int srow = tid >> 2;
    const int kg   = (tid & 3) ^ ((tid >> 3) & 3);
    const unsigned short* Ag = a.A  + (size_t)(m0 + srow) * a.Kd + kg * 8;
    const unsigned short* Bg = a.Bt + (size_t)(n0 + srow) * a.Kd + kg * 8;
    const size_t rstep = (size_t)64 * a.Kd;
    unsigned short* ldsA0 = As + wave * 512;
    unsigned short* ldsA1 = As + 2048 + wave * 512;
    unsigned short* ldsB0 = Bs + wave * 512;
    unsigned short* ldsB1 = Bs + 2048 + wave * 512;

    const int wm = (wave >> 1) << 6;
    const int wn = (wave & 1) << 6;
    const int fm = lane & 15;
    const int fq = lane >> 4;
    const int slot = (fq ^ ((fm >> 1) & 3)) << 3;

    const f32x4 fzero = {0.f, 0.f, 0.f, 0.f};
    f32x4 acc[4][4];
#pragma unroll
    for (int i = 0; i < 4; ++i)
#pragma unroll
        for (int j = 0; j < 4; ++j) acc[i][j] = fzero;

    for (int k0 = 0; k0 < a.Kd; k0 += 32) {
        __syncthreads();
        async_copy16(Ag + k0,         ldsA0);
        async_copy16(Ag + rstep + k0, ldsA1);
        async_copy16(Bg + k0,         ldsB0);
        async_copy16(Bg + rstep + k0, ldsB1);
        __syncthreads();
        bf16x8 af[4], bfr[4];
#pragma unroll
        for (int mt = 0; mt < 4; ++mt)
            af[mt] = *(const bf16x8*)&As[(wm + mt * 16 + fm) * 32 + slot];
#pragma unroll
        for (int nt = 0; nt < 4; ++nt)
            bfr[nt] = *(const bf16x8*)&Bs[(wn + nt * 16 + fm) * 32 + slot];
#pragma unroll
        for (int mt = 0; mt < 4; ++mt)
#pragma unroll
            for (int nt = 0; nt < 4; ++nt)
                acc[mt][nt] = __builtin_amdgcn_mfma_f32_16x16x32_bf16(
                    af[mt], bfr[nt], acc[mt][nt], 0, 0, 0);
    }

    // epilogue — C/D layout: col = lane&15, row = (lane>>4)*4 + reg
    const int cn0 = n0 + wn + fm;
    int cols[4]; float bi[4];
#pragma unroll
    for (int nt = 0; nt < 4; ++nt) {
        const int c = cn0 + nt * 16;
        cols[nt] = c;
        if (EPI == EPI_SPLIT)
            bi[nt] = (c < 512) ? a.bias0[c] : (c < 768) ? a.bias1[c - 512] : a.bias2[c - 768];
        else
            bi[nt] = a.bias0[c];
    }
#pragma unroll
    for (int mt = 0; mt < 4; ++mt) {
#pragma unroll
        for (int r = 0; r < 4; ++r) {
            const int row = m0 + wm + mt * 16 + fq * 4 + r;
            if (row >= a.M) continue;
            const size_t ro = (size_t)row;
            const float* srcres = (EPI == EPI_RESID_SRC)
                                  ? src_row(row, a.s0, a.s1, a.s2, a.s3) : nullptr;
#pragma unroll
            for (int nt = 0; nt < 4; ++nt) {
                float v = acc[mt][nt][r] + bi[nt];
                const int c = cols[nt];
                if (EPI == EPI_SPLIT) {
                    if (c < 512)      ((unsigned short*)a.out0)[ro * 512 + c]        = f2bf(v);
                    else if (c < 768) a.out1[ro * 256 + (c - 512)]                   = f2bf(v);
                    else              a.out2[ro * 128 + (c - 768)]                   = f2bf(v);
                } else if (EPI == EPI_RESID_SRC) {
                    v += srcres[c];
                    ((unsigned short*)a.out0)[ro * 512 + c] = f2bf(v);
                } else if (EPI == EPI_RELU) {
                    v = fmaxf(v, 0.f);
                    ((unsigned short*)a.out0)[ro * 2048 + c] = f2bf(v);
                } else { // EPI_RESID_SCATTER
                    v += bf2f(a.residb[ro * 512 + c]);
                    ((float*)a.out0)[(size_t)permute_row(row) * 512 + c] = v;
                }
            }
        }
    }
}

// ---------------------------------------------------------------------------
// prep: all 6 weight transposes (fp32 [K,N] -> bf16 [N,K]) + Q concat in one
// launch. Blocks [0,2752) = 32x32 transpose tiles; [2752,11082) = concat.
// ---------------------------------------------------------------------------
struct PrepArgs {
    const float *Wv, *Woff, *Wattn, *Wo, *W1, *W2;
    unsigned short *Wcat, *Wot, *W1t, *W2t;
    const float *s0, *s1, *s2, *s3;
    unsigned short* Qb;
};

__global__ __launch_bounds__(256) void prep(PrepArgs p)
{
    __shared__ unsigned short t[32][33];
    const int bid = blockIdx.x;
    if (bid < 2752) {
        const float* W; unsigned short* Wt; int K, N, lbx, rel;
        if (bid < 256)       { W = p.Wv;    Wt = p.Wcat;                   K = 512;  N = 512;  lbx = 4; rel = bid; }
        else if (bid < 384)  { W = p.Woff;  Wt = p.Wcat + (size_t)512*512; K = 512;  N = 256;  lbx = 3; rel = bid - 256; }
        else if (bid < 448)  { W = p.Wattn; Wt = p.Wcat + (size_t)768*512; K = 512;  N = 128;  lbx = 2; rel = bid - 384; }
        else if (bid < 704)  { W = p.Wo;    Wt = p.Wot;                    K = 512;  N = 512;  lbx = 4; rel = bid - 448; }
        else if (bid < 1728) { W = p.W1;    Wt = p.W1t;                    K = 512;  N = 2048; lbx = 6; rel = bid - 704; }
        else                 { W = p.W2;    Wt = p.W2t;                    K = 2048; N = 512;  lbx = 4; rel = bid - 1728; }
        const int bx = rel & ((1 << lbx) - 1);
        const int by = rel >> lbx;
        const int tx = threadIdx.x & 31, ty = threadIdx.x >> 5;
        const int nb = bx * 32, kb = by * 32;
#pragma unroll
        for (int j = 0; j < 32; j += 8)
            t[ty + j][tx] = f2bf(W[(size_t)(kb + ty + j) * N + nb + tx]);
        __syncthreads();
#pragma unroll
        for (int j = 0; j < 32; j += 8)
            Wt[(size_t)(nb + ty + j) * K + kb + tx] = t[tx][ty + j];
    } else {
        const int gid = (bid - 2752) * 256 + threadIdx.x;   // over TTOT*128 exactly
        const int e = gid * 4;
        const int row = e >> 9, col = e & 511;
        const float* sr = src_row(row, p.s0, p.s1, p.s2, p.s3);
        const float4 v = *(const float4*)(sr + col);
        ushort4 o;
        o.x = f2bf(v.x); o.y = f2bf(v.y); o.z = f2bf(v.z); o.w = f2bf(v.w);
        *(ushort4*)(p.Qb + (size_t)row * 512 + col) = o;
    }
}

// ---------------------------------------------------------------------------
// deformable sampling v3: one wave per (token, head-PAIR); block = token.
// Phase 1 (lanes 0-31): lane = (head_local, sample); softmax via width-16
//   shuffles, denom folded into weights; clamped byte indices + validity-
//   zeroed weights -> LDS.
// Phase 2: half-wave = head, lane owns 2 packed bf16 channels (dword loads),
//   16 samples x 4 unconditional corner gathers + fma.
// ---------------------------------------------------------------------------
__global__ __launch_bounds__(256) void sample_attn(
    const unsigned short* __restrict__ Vp, const unsigned short* __restrict__ OFFB,
    const unsigned short* __restrict__ ATT,
    const float* __restrict__ rf0, const float* __restrict__ rf1,
    const float* __restrict__ rf2, const float* __restrict__ rf3,
    unsigned short* __restrict__ ACCb)
{
    __shared__ int   midx[4][2][16][4];
    __shared__ float mw[4][2][16][4];
    const int wave = threadIdx.x >> 6;     // = head pair hp (block = token)
    const int lane = threadIdx.x & 63;
    const int t  = blockIdx.x;
    const int hp = wave;

    int soff, area;
    const float* rp;
    if (t < 12544)      { soff = 0;     area = 3136; rp = rf0 + (size_t)t * 2; }
    else if (t < 15680) { soff = 12544; area = 784;  rp = rf1 + (size_t)(t - 12544) * 2; }
    else if (t < 16464) { soff = 15680; area = 196;  rp = rf2 + (size_t)(t - 15680) * 2; }
    else                { soff = 16464; area = 49;   rp = rf3 + (size_t)(t - 16464) * 2; }
    const int b = (t - soff) / area;

    if (lane < 32) {
        const int hl = lane >> 4;          // head within pair
        const int s  = lane & 15;          // (level,k) sample
        const int h  = hp * 2 + hl;
        const int li = s >> 2;
        // softmax over 16 logits of this head (width-16 shuffle groups)
        float logit = bf2f(ATT[(size_t)t * 128 + h * 16 + s]);
        float mx = logit;
#pragma unroll
        for (int o = 8; o > 0; o >>= 1) mx = fmaxf(mx, __shfl_xor(mx, o, 16));
        float e = __expf(logit - mx);
        float sumv = e;
#pragma unroll
        for (int o = 8; o > 0; o >>= 1) sumv += __shfl_xor(sumv, o, 16);
        const float ew = e / sumv;         // denom folded in here

        // coords: (rx + ox/wl)*wl - 0.5 == rx*wl + ox - 0.5
        const int wl = 56 >> li;
        const int lvlbase = (li == 0) ? 0 : (li == 1) ? 12544 : (li == 2) ? 15680 : 16464;
        const int base = lvlbase + b * wl * wl;
        const float rx = rp[0], ry = rp[1];
        const unsigned off2 = *(const unsigned*)(OFFB + (size_t)t * 256 + h * 32 + s * 2);
        const float ox = bflo(off2);
        const float oy = bfhi(off2);
        const float x = rx * (float)wl + ox - 0.5f;
        const float y = ry * (float)wl + oy - 0.5f;
        const float x0f = floorf(x), y0f = floorf(y);
        const float wx1 = x - x0f, wx0 = 1.f - wx1;
        const float wy1 = y - y0f, wy0 = 1.f - wy1;
        const int x0 = (int)x0f, y0 = (int)y0f;
        const int x1 = x0 + 1, y1 = y0 + 1;
        const int xc0 = min(max(x0, 0), wl - 1), xc1 = min(max(x1, 0), wl - 1);
        const int yc0 = min(max(y0, 0), wl - 1), yc1 = min(max(y1, 0), wl - 1);
        const float fx0 = (x0 >= 0 && x0 < wl) ? 1.f : 0.f;
        const float fx1 = (x1 >= 0 && x1 < wl) ? 1.f : 0.f;
        const float fy0 = (y0 >= 0 && y0 < wl) ? 1.f : 0.f;
        const float fy1 = (y1 >= 0 && y1 < wl) ? 1.f : 0.f;
        const int hb2 = h * 128;           // head base, BYTES (h*64 ch * 2B)
        midx[wave][hl][s][0] = (base + yc0 * wl + xc0) * 1024 + hb2;   // *512 elem *2B
        midx[wave][hl][s][1] = (base + yc0 * wl + xc1) * 1024 + hb2;
        midx[wave][hl][s][2] = (base + yc1 * wl + xc0) * 1024 + hb2;
        midx[wave][hl][s][3] = (base + yc1 * wl + xc1) * 1024 + hb2;
        mw[wave][hl][s][0] = wx0 * wy0 * fx0 * fy0 * ew;
        mw[wave][hl][s][1] = wx1 * wy0 * fx1 * fy0 * ew;
        mw[wave][hl][s][2] = wx0 * wy1 * fx0 * fy1 * ew;
        mw[wave][hl][s][3] = wx1 * wy1 * fx1 * fy1 * ew;
    }
    __syncthreads();

    // phase 2: half-wave = head, lane owns channels 2*(lane&31), +1
    const int hl = lane >> 5;
    const int laneoff = (lane & 31) * 4;   // bytes within head's 128-byte row
    const char* vb = (const char*)Vp;
    float accL = 0.f, accH = 0.f;
#pragma unroll
    for (int s = 0; s < 16; ++s) {
        const int4   I = *(const int4*)&midx[wave][hl][s][0];
        const float4 W = *(const float4*)&mw[wave][hl][s][0];
        const unsigned u0 = *(const unsigned*)(vb + (I.x + laneoff));
        const unsigned u1 = *(const unsigned*)(vb + (I.y + laneoff));
        const unsigned u2 = *(const unsigned*)(vb + (I.z + laneoff));
        const unsigned u3 = *(const unsigned*)(vb + (I.w + laneoff));
        accL += W.x * bflo(u0); accH += W.x * bfhi(u0);
        accL += W.y * bflo(u1); accH += W.y * bfhi(u1);
        accL += W.z * bflo(u2); accH += W.z * bfhi(u2);
        accL += W.w * bflo(u3); accH += W.w * bfhi(u3);
    }
    const int h = hp * 2 + hl;
    ushort2 o;
    o.x = f2bf(accL);
    o.y = f2bf(accH);
    *(ushort2*)((char*)ACCb + (size_t)t * 1024 + h * 128 + laneoff) = o;
}

// in-place layernorm on bf16 rows of 512 (fp32 stats)
__global__ __launch_bounds__(256) void ln_bf16(
    unsigned short* __restrict__ X, const float* __restrict__ g, const float* __restrict__ be)
{
    const int row = blockIdx.x;
    unsigned short* xr = X + (size_t)row * 512;
    const int tid = threadIdx.x;
    float v0 = bf2f(xr[tid]);
    float v1 = bf2f(xr[tid + 256]);
    float s = v0 + v1;
    float ss = v0 * v0 + v1 * v1;
#pragma unroll
    for (int o = 32; o > 0; o >>= 1) {
        s += __shfl_down(s, o, 64);
        ss += __shfl_down(ss, o, 64);
    }
    __shared__ float sm[4], sm2[4];
    const int w = tid >> 6;
    if ((tid & 63) == 0) { sm[w] = s; sm2[w] = ss; }
    __syncthreads();
    if (tid == 0) {
        sm[0] = sm[0] + sm[1] + sm[2] + sm[3];
        sm2[0] = sm2[0] + sm2[1] + sm2[2] + sm2[3];
    }
    __syncthreads();
    const float mu = sm[0] * (1.f / 512.f);
    const float var = sm2[0] * (1.f / 512.f) - mu * mu;
    const float rs = rsqrtf(var + 1e-5f);
    xr[tid]       = f2bf((v0 - mu) * rs * g[tid]       + be[tid]);
    xr[tid + 256] = f2bf((v1 - mu) * rs * g[tid + 256] + be[tid + 256]);
}

// in-place fp32 layernorm (final, on d_out)
__global__ __launch_bounds__(256) void ln_f32(
    float* __restrict__ X, const float* __restrict__ g, const float* __restrict__ be)
{
    const int row = blockIdx.x;
    float* xr = X + (size_t)row * 512;
    const int tid = threadIdx.x;
    float v0 = xr[tid];
    float v1 = xr[tid + 256];
    float s = v0 + v1;
    float ss = v0 * v0 + v1 * v1;
#pragma unroll
    for (int o = 32; o > 0; o >>= 1) {
        s += __shfl_down(s, o, 64);
        ss += __shfl_down(ss, o, 64);
    }
    __shared__ float sm[4], sm2[4];
    const int w = tid >> 6;
    if ((tid & 63) == 0) { sm[w] = s; sm2[w] = ss; }
    __syncthreads();
    if (tid == 0) {
        sm[0] = sm[0] + sm[1] + sm[2] + sm[3];
        sm2[0] = sm2[0] + sm2[1] + sm2[2] + sm2[3];
    }
    __syncthreads();
    const float mu = sm[0] * (1.f / 512.f);
    const float var = sm2[0] * (1.f / 512.f) - mu * mu;
    const float rs = rsqrtf(var + 1e-5f);
    xr[tid]       = (v0 - mu) * rs * g[tid]       + be[tid];
    xr[tid + 256] = (v1 - mu) * rs * g[tid + 256] + be[tid + 256];
}

extern "C" void kernel_launch(void* const* d_in, const int* in_sizes, int n_in,
                              void* d_out, int out_size, void* d_ws, size_t ws_size,
                              hipStream_t stream)
{
    const float* src[4] = { (const float*)d_in[0], (const float*)d_in[2],
                            (const float*)d_in[4], (const float*)d_in[6] };
    const float* ref[4] = { (const float*)d_in[1], (const float*)d_in[3],
                            (const float*)d_in[5], (const float*)d_in[7] };
    const float* Wv    = (const float*)d_in[8];
    const float* bv    = (const float*)d_in[9];
    const float* Woff  = (const float*)d_in[10];
    const float* boff  = (const float*)d_in[11];
    const float* Wattn = (const float*)d_in[12];
    const float* battn = (const float*)d_in[13];
    const float* Wo    = (const float*)d_in[14];
    const float* bo    = (const float*)d_in[15];
    const float* W1    = (const float*)d_in[16];
    const float* b1    = (const float*)d_in[17];
    const float* W2    = (const float*)d_in[18];
    const float* b2    = (const float*)d_in[19];
    const float* g1    = (const float*)d_in[20];
    const float* be1   = (const float*)d_in[21];
    const float* g2    = (const float*)d_in[22];
    const float* be2   = (const float*)d_in[23];

    // workspace layout (bf16 == unsigned short)
    unsigned short* w    = (unsigned short*)d_ws;
    unsigned short* Qb   = w;                              // [TPAD,512]
    unsigned short* Vp   = Qb   + (size_t)TPAD * 512;      // [TPAD,512]
    unsigned short* OFFB = Vp   + (size_t)TPAD * 512;      // [TPAD,256]
    unsigned short* ATT  = OFFB + (size_t)TPAD * 256;      // [TPAD,128]
    unsigned short* ACCb = ATT  + (size_t)TPAD * 128;      // [TPAD,512]
    unsigned short* X1b  = ACCb + (size_t)TPAD * 512;      // [TPAD,512]
    unsigned short* Fb   = X1b  + (size_t)TPAD * 512;      // [TPAD,2048]
    unsigned short* Wcat = Fb   + (size_t)TPAD * 2048;     // [896,512]
    unsigned short* Wot  = Wcat + (size_t)896 * 512;       // [512,512]
    unsigned short* W1t  = Wot  + (size_t)512 * 512;       // [2048,512]
    unsigned short* W2t  = W1t  + (size_t)2048 * 512;      // [512,2048]

    const dim3 blk(256);

    PrepArgs pp = {};
    pp.Wv = Wv; pp.Woff = Woff; pp.Wattn = Wattn; pp.Wo = Wo; pp.W1 = W1; pp.W2 = W2;
    pp.Wcat = Wcat; pp.Wot = Wot; pp.W1t = W1t; pp.W2t = W2t;
    pp.s0 = src[0]; pp.s1 = src[1]; pp.s2 = src[2]; pp.s3 = src[3];
    pp.Qb = Qb;
    prep<<<dim3(11082), blk, 0, stream>>>(pp);

    // fused V/off/attn projection: [T,512] @ [512,896]
    GemmArgs a1 = {};
    a1.A = Qb; a1.Bt = Wcat; a1.bias0 = bv; a1.bias1 = boff; a1.bias2 = battn;
    a1.out0 = Vp; a1.out1 = OFFB; a1.out2 = ATT; a1.M = TTOT; a1.N = 896; a1.Kd = 512;
    gemm_mfma<EPI_SPLIT><<<dim3(7, 131), blk, 0, stream>>>(a1);

    sample_attn<<<dim3(TTOT), blk, 0, stream>>>(Vp, OFFB, ATT,
                                                ref[0], ref[1], ref[2], ref[3], ACCb);

    // output projection + residual(q from srcs)
    GemmArgs a2 = {};
    a2.A = ACCb; a2.Bt = Wot; a2.bias0 = bo;
    a2.s0 = src[0]; a2.s1 = src[1]; a2.s2 = src[2]; a2.s3 = src[3];
    a2.out0 = X1b; a2.M = TTOT; a2.N = 512; a2.Kd = 512;
    gemm_mfma<EPI_RESID_SRC><<<dim3(4, 131), blk, 0, stream>>>(a2);

    ln_bf16<<<dim3(TTOT), blk, 0, stream>>>(X1b, g1, be1);

    // FFN up + relu
    GemmArgs a3 = {};
    a3.A = X1b; a3.Bt = W1t; a3.bias0 = b1;
    a3.out0 = Fb; a3.M = TTOT; a3.N = 2048; a3.Kd = 512;
    gemm_mfma<EPI_RELU><<<dim3(16, 131), blk, 0, stream>>>(a3);

    // FFN down + residual(x) + scatter into d_out layout
    GemmArgs a4 = {};
    a4.A = Fb; a4.Bt = W2t; a4.bias0 = b2; a4.residb = X1b;
    a4.out0 = d_out; a4.M = TTOT; a4.N = 512; a4.Kd = 2048;
    gemm_mfma<EPI_RESID_SCATTER><<<dim3(4, 131), blk, 0, stream>>>(a4);

    ln_f32<<<dim3(TTOT), blk, 0, stream>>>((float*)d_out, g2, be2);
}